// Round 3
// baseline (256.075 us; speedup 1.0000x reference)
//
#include <hip/hip_runtime.h>

#define BB 32
#define NN_ 128
#define NIN 64
#define MH 256
#define MO 64
#define NH 256
#define NO 64
#define EDGES 16256

typedef _Float16 half8 __attribute__((ext_vector_type(8)));   // 8 f16 = 4 VGPRs
typedef __attribute__((ext_vector_type(4))) float f32x4;      // MFMA acc

// ws layout (floats):
//   psb: [B][32][128][8] f16   off 0        = 524288 floats
//   prb: [B][N][256]     f16   off 524288   = 524288 floats
//   w2b: [32][64][8]     f16   off 1048576  = 8192 floats
//   o1b: [256][64]       f16   off 1056768  = 8192 floats
//   o2b: [256][256]      f16   off 1064960  = 32768 floats
//   o3b: [64][256]       f16   off 1097728  = 8192 floats

static __device__ __forceinline__ unsigned short f2h(float f) {
    return __builtin_bit_cast(unsigned short, (_Float16)f);   // v_cvt_f16_f32
}

// pack 8 fp32 -> 8 f16 via 4x v_cvt_pkrtz_f16_f32 (1 inst per pair)
static __device__ __forceinline__ half8 pack8h(float4 f0, float4 f1) {
    uint4 u;
    u.x = __builtin_bit_cast(unsigned, __builtin_amdgcn_cvt_pkrtz(f0.x, f0.y));
    u.y = __builtin_bit_cast(unsigned, __builtin_amdgcn_cvt_pkrtz(f0.z, f0.w));
    u.z = __builtin_bit_cast(unsigned, __builtin_amdgcn_cvt_pkrtz(f1.x, f1.y));
    u.w = __builtin_bit_cast(unsigned, __builtin_amdgcn_cvt_pkrtz(f1.z, f1.w));
    return __builtin_bit_cast(half8, u);
}

// relu(s + p) fully in packed-f16 domain: 4x v_pk_add_f16 + 4x v_pk_max_f16
static __device__ __forceinline__ half8 addrelu(uint4 s, uint4 p) {
    half8 a = __builtin_bit_cast(half8, s) + __builtin_bit_cast(half8, p);
    half8 z = {};
    return __builtin_elementwise_max(a, z);
}

// ---------------------------------------------------------------------------
// Kernel 1: prep (unchanged structure).
//   blocks 0..255   : fc1 partials via f16 MFMA -> psb/prb
//   blocks 256..319 : W2 -> f16 re-layout w2b[kc4][n][k7]
//   blocks 320..703 : O1/O2/O3 -> f16 casts
// ---------------------------------------------------------------------------
__global__ __launch_bounds__(256) void prep_kernel(
    const float* __restrict__ x, const float* __restrict__ W1,
    const float* __restrict__ b1, const float* __restrict__ W2,
    const float* __restrict__ O1, const float* __restrict__ O2,
    const float* __restrict__ O3,
    unsigned short* __restrict__ psb, unsigned short* __restrict__ prb,
    unsigned short* __restrict__ w2b, unsigned short* __restrict__ o1b,
    unsigned short* __restrict__ o2b, unsigned short* __restrict__ o3b)
{
    int blk = blockIdx.x;
    int t = threadIdx.x;
    if (blk < 256) {
        int row0 = blk << 4;          // 16 consecutive global rows (b = blk>>3)
        int b = blk >> 3;
        int w = t >> 6, lane = t & 63, ml = lane & 15, q = lane >> 4;

        half8 aX[2];
        #pragma unroll
        for (int s = 0; s < 2; ++s) {
            const float* base = x + (size_t)(row0 + ml) * NIN + s * 32 + q * 8;
            aX[s] = pack8h(*(const float4*)base, *(const float4*)(base + 4));
        }

        #pragma unroll
        for (int half = 0; half < 2; ++half) {     // 0 = sender(ps), 1 = recv(pr)
            #pragma unroll
            for (int nt = 0; nt < 4; ++nt) {
                int col = w * 64 + nt * 16 + ml;   // output unit h (0..255)
                const float* wrow = W1 + (size_t)col * (2 * NIN) + half * 64 + q * 8;
                f32x4 acc = (f32x4){0.f, 0.f, 0.f, 0.f};
                #pragma unroll
                for (int s = 0; s < 2; ++s) {
                    half8 bw = pack8h(*(const float4*)(wrow + 32 * s),
                                      *(const float4*)(wrow + 32 * s + 4));
                    acc = __builtin_amdgcn_mfma_f32_16x16x32_f16(aX[s], bw, acc, 0, 0, 0);
                }
                if (half == 0) {
                    #pragma unroll
                    for (int reg = 0; reg < 4; ++reg) {
                        int n = (row0 + q * 4 + reg) & 127;
                        psb[((size_t)(b * 32 + (col >> 3)) * NN_ + n) * 8 + (col & 7)]
                            = f2h(acc[reg]);
                    }
                } else {
                    float bv = b1[col];
                    #pragma unroll
                    for (int reg = 0; reg < 4; ++reg) {
                        int n = (row0 + q * 4 + reg) & 127;
                        prb[((size_t)(b * NN_) + n) * MH + col] = f2h(acc[reg] + bv);
                    }
                }
            }
        }
    } else if (blk < 320) {
        int i = ((blk - 256) << 8) + t;   // 0..16383
        int kc4 = i >> 9, rem = i & 511;
        int n = rem >> 3, k7 = i & 7;
        w2b[i] = f2h(W2[n * MH + kc4 * 8 + k7]);   // w2b[kc4][n][k7] = W2[n][k]
    } else {
        int i = ((blk - 320) << 8) + t;   // 0..98303
        if (i < 16384)       o1b[i]         = f2h(O1[i]);
        else if (i < 81920)  o2b[i - 16384] = f2h(O2[i - 16384]);
        else                 o3b[i - 81920] = f2h(O3[i - 81920]);
    }
}

// ---------------------------------------------------------------------------
// Kernel 2: edge fc2 + segment-sum + node MLP, fused per block.
// Grid 512 x 512 threads (8 waves = 2 teams of 4). Block owns 8 consecutive
// receivers of one batch: team tt handles unit blk*4 + uu*2 + tt (uu=0..1),
// each unit = 2 receivers, agg rows land in LDS (no global roundtrip, no
// grid barrier needed: the sender-sum is block-local by construction).
// Then 8 waves run the 3-layer node MLP on rows 0..7 (rows 8..15 zero-pad).
// __launch_bounds__(512,4): 2 blocks/CU -> 16 waves/CU during edge phase.
// ---------------------------------------------------------------------------
__global__ __launch_bounds__(512, 4) void edge_node_kernel(
    const float* __restrict__ rt, const float* __restrict__ b2,
    const unsigned short* __restrict__ psb, const unsigned short* __restrict__ prb,
    const unsigned short* __restrict__ w2b,
    const unsigned short* __restrict__ o1b, const float* __restrict__ b1o,
    const unsigned short* __restrict__ o2b, const float* __restrict__ b2o,
    const unsigned short* __restrict__ o3b, const float* __restrict__ b3o,
    float* __restrict__ out)
{
    int blk = blockIdx.x;          // 0..511
    int t = threadIdx.x;           // 0..511
    int team = t >> 8;             // 0,1
    int tl = t & 255;              // thread-in-team
    int w = tl >> 6;               // wave-in-team 0..3
    int lane = t & 63;
    int ml = lane & 15, q = lane >> 4;

    int b = blk >> 4;              // batch (16 blocks per batch)
    int rbase = (blk & 15) << 3;   // first of this block's 8 receivers

    __shared__ float rtw_lds[2][2][128];   // [team][rr][sender]
    __shared__ float red[2][2][4][64];     // [team][rr][wave][o]
    __shared__ float aggL[16][68];         // rows 0..7 data, 8..15 zero, pad->68
    __shared__ unsigned short h1L[16][264];
    __shared__ unsigned short h2L[16][264];

    // zero-pad rows 8..15 (node MFMA reads 16 rows; only 8 are real)
    aggL[8 + (t >> 6)][lane] = 0.f;

    float b2c[4];
    #pragma unroll
    for (int nt = 0; nt < 4; ++nt) b2c[nt] = b2[16 * nt + ml];

    const uint4* ps4 = (const uint4*)psb + (size_t)b * (32 * NN_);   // [kc4][node]
    const uint4* w24 = (const uint4*)w2b;                            // [kc4][n]

    #pragma unroll 1
    for (int uu = 0; uu < 2; ++uu) {
        int lr = uu * 2 + team;            // local receiver-pair 0..3
        int r0 = rbase + lr * 2;           // first receiver of this unit

        __syncthreads();                   // protect rtw/red reuse across uu
        {
            int rr = tl >> 7, s = tl & 127;
            int r = r0 + rr;
            float v = 0.f;
            if (s != r) {
                int e = r * 127 + s - (s > r ? 1 : 0);
                const float* p = rt + ((size_t)(b * EDGES + e)) * 2;
                v = p[0] + p[1];
            }
            rtw_lds[team][rr][s] = v;
        }
        __syncthreads();

        int slot0 = 32 * w + ml;
        int slot1 = slot0 + 16;

        const uint4* pr4_0 = (const uint4*)(prb + ((size_t)(b * NN_ + r0)) * MH);
        const uint4* pr4_1 = (const uint4*)(prb + ((size_t)(b * NN_ + r0 + 1)) * MH);

        f32x4 acc[2][2][4];   // [receiver][m-tile][n-tile]
        #pragma unroll
        for (int rr = 0; rr < 2; ++rr)
            #pragma unroll
            for (int mt = 0; mt < 2; ++mt)
                #pragma unroll
                for (int nt = 0; nt < 4; ++nt)
                    acc[rr][mt][nt] = (f32x4){0.f, 0.f, 0.f, 0.f};

        #pragma unroll
        for (int kc = 0; kc < 8; ++kc) {
            int kc4 = 4 * kc + q;
            uint4 us0 = ps4[kc4 * NN_ + slot0];
            uint4 us1 = ps4[kc4 * NN_ + slot1];
            uint4 up0 = pr4_0[kc4];
            uint4 up1 = pr4_1[kc4];

            half8 a00 = addrelu(us0, up0);   // r0, m-tile 0
            half8 a01 = addrelu(us1, up0);   // r0, m-tile 1
            half8 a10 = addrelu(us0, up1);   // r1, m-tile 0
            half8 a11 = addrelu(us1, up1);   // r1, m-tile 1

            #pragma unroll
            for (int nt = 0; nt < 4; ++nt) {
                half8 bw = __builtin_bit_cast(half8, w24[kc4 * 64 + 16 * nt + ml]);
                acc[0][0][nt] = __builtin_amdgcn_mfma_f32_16x16x32_f16(a00, bw, acc[0][0][nt], 0, 0, 0);
                acc[0][1][nt] = __builtin_amdgcn_mfma_f32_16x16x32_f16(a01, bw, acc[0][1][nt], 0, 0, 0);
                acc[1][0][nt] = __builtin_amdgcn_mfma_f32_16x16x32_f16(a10, bw, acc[1][0][nt], 0, 0, 0);
                acc[1][1][nt] = __builtin_amdgcn_mfma_f32_16x16x32_f16(a11, bw, acc[1][1][nt], 0, 0, 0);
            }
        }

        #pragma unroll
        for (int rr = 0; rr < 2; ++rr) {
            float colsum[4] = {0.f, 0.f, 0.f, 0.f};
            #pragma unroll
            for (int mt = 0; mt < 2; ++mt) {
                int slotbase = 32 * w + 16 * mt + 4 * q;
                #pragma unroll
                for (int reg = 0; reg < 4; ++reg) {
                    float rw = rtw_lds[team][rr][slotbase + reg];
                    #pragma unroll
                    for (int nt = 0; nt < 4; ++nt)
                        colsum[nt] += fmaxf(acc[rr][mt][nt][reg] + b2c[nt], 0.f) * rw;
                }
            }
            #pragma unroll
            for (int nt = 0; nt < 4; ++nt) {
                colsum[nt] += __shfl_xor(colsum[nt], 16);
                colsum[nt] += __shfl_xor(colsum[nt], 32);
            }
            if (lane < 16) {
                #pragma unroll
                for (int nt = 0; nt < 4; ++nt)
                    red[team][rr][w][16 * nt + ml] = colsum[nt];
            }
        }
        __syncthreads();
        if (tl < 128) {
            int rr = tl >> 6, o = tl & 63;
            aggL[lr * 2 + rr][o] =
                red[team][rr][0][o] + red[team][rr][1][o] +
                red[team][rr][2][o] + red[team][rr][3][o];
        }
    }
    __syncthreads();

    // ------------------------------- node MLP -------------------------------
    int wv = t >> 6;   // wave 0..7

    half8 aA[2];
    #pragma unroll
    for (int s = 0; s < 2; ++s) {
        const float* base = &aggL[ml][32 * s + q * 8];
        aA[s] = pack8h(*(const float4*)base, *(const float4*)(base + 4));
    }

    // fc1: [16 x 64] @ [64 x 256]  (16 n-tiles over 8 waves)
    #pragma unroll
    for (int nt = 0; nt < 2; ++nt) {
        int ntg = wv * 2 + nt;
        f32x4 acc = (f32x4){0.f, 0.f, 0.f, 0.f};
        #pragma unroll
        for (int s = 0; s < 2; ++s) {
            half8 bw = *(const half8*)(o1b + (size_t)(ntg * 16 + ml) * 64 + 32 * s + q * 8);
            acc = __builtin_amdgcn_mfma_f32_16x16x32_f16(aA[s], bw, acc, 0, 0, 0);
        }
        float bv = b1o[ntg * 16 + ml];
        #pragma unroll
        for (int reg = 0; reg < 4; ++reg)
            h1L[q * 4 + reg][ntg * 16 + ml] = f2h(fmaxf(acc[reg] + bv, 0.f));
    }
    __syncthreads();

    // fc2: [16 x 256] @ [256 x 256]
    half8 aH[8];
    #pragma unroll
    for (int ks = 0; ks < 8; ++ks)
        aH[ks] = *(const half8*)&h1L[ml][32 * ks + q * 8];
    #pragma unroll
    for (int nt = 0; nt < 2; ++nt) {
        int ntg = wv * 2 + nt;
        const unsigned short* wrow = o2b + (size_t)(ntg * 16 + ml) * NH + q * 8;
        f32x4 acc = (f32x4){0.f, 0.f, 0.f, 0.f};
        #pragma unroll
        for (int ks = 0; ks < 8; ++ks) {
            half8 bw = *(const half8*)(wrow + 32 * ks);
            acc = __builtin_amdgcn_mfma_f32_16x16x32_f16(aH[ks], bw, acc, 0, 0, 0);
        }
        float bv = b2o[ntg * 16 + ml];
        #pragma unroll
        for (int reg = 0; reg < 4; ++reg)
            h2L[q * 4 + reg][ntg * 16 + ml] = f2h(fmaxf(acc[reg] + bv, 0.f));
    }
    __syncthreads();

    // fc3: [16 x 256] @ [256 x 64]  (4 n-tiles, waves 0..3)
    if (wv < 4) {
        #pragma unroll
        for (int ks = 0; ks < 8; ++ks)
            aH[ks] = *(const half8*)&h2L[ml][32 * ks + q * 8];
        const unsigned short* wrow = o3b + (size_t)(wv * 16 + ml) * NH + q * 8;
        f32x4 acc = (f32x4){0.f, 0.f, 0.f, 0.f};
        #pragma unroll
        for (int ks = 0; ks < 8; ++ks) {
            half8 bw = *(const half8*)(wrow + 32 * ks);
            acc = __builtin_amdgcn_mfma_f32_16x16x32_f16(aH[ks], bw, acc, 0, 0, 0);
        }
        float bv = b3o[wv * 16 + ml];
        if (q < 2) {   // only rows 0..7 are real
            #pragma unroll
            for (int reg = 0; reg < 4; ++reg)
                out[(size_t)(b * NN_ + rbase + q * 4 + reg) * NO + wv * 16 + ml]
                    = acc[reg] + bv;
        }
    }
}

// ---------------------------------------------------------------------------
extern "C" void kernel_launch(void* const* d_in, const int* in_sizes, int n_in,
                              void* d_out, int out_size, void* d_ws, size_t ws_size,
                              hipStream_t stream) {
    const float* x   = (const float*)d_in[0];
    const float* rt  = (const float*)d_in[3];
    const float* W1  = (const float*)d_in[4];
    const float* b1  = (const float*)d_in[5];
    const float* W2  = (const float*)d_in[6];
    const float* b2  = (const float*)d_in[7];
    const float* O1  = (const float*)d_in[8];
    const float* b1o = (const float*)d_in[9];
    const float* O2  = (const float*)d_in[10];
    const float* b2o = (const float*)d_in[11];
    const float* O3  = (const float*)d_in[12];
    const float* b3o = (const float*)d_in[13];

    float* ws  = (float*)d_ws;
    unsigned short* psb = (unsigned short*)ws;
    unsigned short* prb = (unsigned short*)(ws + 524288);
    unsigned short* w2b = (unsigned short*)(ws + 1048576);
    unsigned short* o1b = (unsigned short*)(ws + 1056768);
    unsigned short* o2b = (unsigned short*)(ws + 1064960);
    unsigned short* o3b = (unsigned short*)(ws + 1097728);
    float* out = (float*)d_out;

    hipLaunchKernelGGL(prep_kernel, dim3(704), dim3(256), 0, stream,
                       x, W1, b1, W2, O1, O2, O3, psb, prb, w2b, o1b, o2b, o3b);
    hipLaunchKernelGGL(edge_node_kernel, dim3(512), dim3(512), 0, stream,
                       rt, b2, psb, prb, w2b, o1b, b1o, o2b, b2o, o3b, b3o, out);
}

// Round 4
// 174.334 us; speedup vs baseline: 1.4689x; 1.4689x over previous
//
#include <hip/hip_runtime.h>

#define BB 32
#define NN_ 128
#define NIN 64
#define MH 256
#define MO 64
#define NH 256
#define NO 64
#define EDGES 16256

typedef _Float16 half8 __attribute__((ext_vector_type(8)));   // 8 f16 = 4 VGPRs
typedef __attribute__((ext_vector_type(4))) float f32x4;      // MFMA acc

// ws layout (floats):
//   psb: [B][32][128][8] f16   off 0        = 524288 floats
//   prb: [B][N][256]     f16   off 524288   = 524288 floats
//   w2b: [32][64][8]     f16   off 1048576  = 8192 floats
//   o1b: [256][64]       f16   off 1056768  = 8192 floats
//   o2b: [256][256]      f16   off 1064960  = 32768 floats
//   o3b: [64][256]       f16   off 1097728  = 8192 floats

static __device__ __forceinline__ unsigned short f2h(float f) {
    return __builtin_bit_cast(unsigned short, (_Float16)f);   // v_cvt_f16_f32
}

// pack 8 fp32 -> 8 f16 via 4x v_cvt_pkrtz_f16_f32 (1 inst per pair)
static __device__ __forceinline__ half8 pack8h(float4 f0, float4 f1) {
    uint4 u;
    u.x = __builtin_bit_cast(unsigned, __builtin_amdgcn_cvt_pkrtz(f0.x, f0.y));
    u.y = __builtin_bit_cast(unsigned, __builtin_amdgcn_cvt_pkrtz(f0.z, f0.w));
    u.z = __builtin_bit_cast(unsigned, __builtin_amdgcn_cvt_pkrtz(f1.x, f1.y));
    u.w = __builtin_bit_cast(unsigned, __builtin_amdgcn_cvt_pkrtz(f1.z, f1.w));
    return __builtin_bit_cast(half8, u);
}

// relu(s + p) fully in packed-f16 domain: 4x v_pk_add_f16 + 4x v_pk_max_f16
static __device__ __forceinline__ half8 addrelu(uint4 s, uint4 p) {
    half8 a = __builtin_bit_cast(half8, s) + __builtin_bit_cast(half8, p);
    half8 z = {};
    return __builtin_elementwise_max(a, z);
}

// ---------------------------------------------------------------------------
// Kernel 1: prep (unchanged structure).
//   blocks 0..255   : fc1 partials via f16 MFMA -> psb/prb
//   blocks 256..319 : W2 -> f16 re-layout w2b[kc4][n][k7]
//   blocks 320..703 : O1/O2/O3 -> f16 casts
// ---------------------------------------------------------------------------
__global__ __launch_bounds__(256) void prep_kernel(
    const float* __restrict__ x, const float* __restrict__ W1,
    const float* __restrict__ b1, const float* __restrict__ W2,
    const float* __restrict__ O1, const float* __restrict__ O2,
    const float* __restrict__ O3,
    unsigned short* __restrict__ psb, unsigned short* __restrict__ prb,
    unsigned short* __restrict__ w2b, unsigned short* __restrict__ o1b,
    unsigned short* __restrict__ o2b, unsigned short* __restrict__ o3b)
{
    int blk = blockIdx.x;
    int t = threadIdx.x;
    if (blk < 256) {
        int row0 = blk << 4;          // 16 consecutive global rows (b = blk>>3)
        int b = blk >> 3;
        int w = t >> 6, lane = t & 63, ml = lane & 15, q = lane >> 4;

        half8 aX[2];
        #pragma unroll
        for (int s = 0; s < 2; ++s) {
            const float* base = x + (size_t)(row0 + ml) * NIN + s * 32 + q * 8;
            aX[s] = pack8h(*(const float4*)base, *(const float4*)(base + 4));
        }

        #pragma unroll
        for (int half = 0; half < 2; ++half) {     // 0 = sender(ps), 1 = recv(pr)
            #pragma unroll
            for (int nt = 0; nt < 4; ++nt) {
                int col = w * 64 + nt * 16 + ml;   // output unit h (0..255)
                const float* wrow = W1 + (size_t)col * (2 * NIN) + half * 64 + q * 8;
                f32x4 acc = (f32x4){0.f, 0.f, 0.f, 0.f};
                #pragma unroll
                for (int s = 0; s < 2; ++s) {
                    half8 bw = pack8h(*(const float4*)(wrow + 32 * s),
                                      *(const float4*)(wrow + 32 * s + 4));
                    acc = __builtin_amdgcn_mfma_f32_16x16x32_f16(aX[s], bw, acc, 0, 0, 0);
                }
                if (half == 0) {
                    #pragma unroll
                    for (int reg = 0; reg < 4; ++reg) {
                        int n = (row0 + q * 4 + reg) & 127;
                        psb[((size_t)(b * 32 + (col >> 3)) * NN_ + n) * 8 + (col & 7)]
                            = f2h(acc[reg]);
                    }
                } else {
                    float bv = b1[col];
                    #pragma unroll
                    for (int reg = 0; reg < 4; ++reg) {
                        int n = (row0 + q * 4 + reg) & 127;
                        prb[((size_t)(b * NN_) + n) * MH + col] = f2h(acc[reg] + bv);
                    }
                }
            }
        }
    } else if (blk < 320) {
        int i = ((blk - 256) << 8) + t;   // 0..16383
        int kc4 = i >> 9, rem = i & 511;
        int n = rem >> 3, k7 = i & 7;
        w2b[i] = f2h(W2[n * MH + kc4 * 8 + k7]);   // w2b[kc4][n][k7] = W2[n][k]
    } else {
        int i = ((blk - 320) << 8) + t;   // 0..98303
        if (i < 16384)       o1b[i]         = f2h(O1[i]);
        else if (i < 81920)  o2b[i - 16384] = f2h(O2[i - 16384]);
        else                 o3b[i - 81920] = f2h(O3[i - 81920]);
    }
}

// ---------------------------------------------------------------------------
// Kernel 2: edge fc2 + segment-sum + node MLP, fused per block.
// Grid 512 x 512 threads (8 waves = 2 teams of 4). Block owns 8 consecutive
// receivers of one batch: team tt handles unit blk*4 + uu*2 + tt (uu=0..1),
// each unit = 2 receivers, agg rows land in LDS (no global roundtrip, no
// grid barrier needed: the sender-sum is block-local by construction).
// Then 8 waves run the 3-layer node MLP on rows 0..7 (rows 8..15 zero-pad).
//
// NOTE (R3 post-mortem, measured): __launch_bounds__(512,4) capped VGPRs at
// 64 -> acc[2][2][4] alone is 64 regs -> 444 MB of scratch spill traffic,
// 170 us. Second arg empirically acts as blocks/CU on this toolchain.
// Plain (512) lets the allocator take ~128 regs, no spill.
// ---------------------------------------------------------------------------
__global__ __launch_bounds__(512) void edge_node_kernel(
    const float* __restrict__ rt, const float* __restrict__ b2,
    const unsigned short* __restrict__ psb, const unsigned short* __restrict__ prb,
    const unsigned short* __restrict__ w2b,
    const unsigned short* __restrict__ o1b, const float* __restrict__ b1o,
    const unsigned short* __restrict__ o2b, const float* __restrict__ b2o,
    const unsigned short* __restrict__ o3b, const float* __restrict__ b3o,
    float* __restrict__ out)
{
    int blk = blockIdx.x;          // 0..511
    int t = threadIdx.x;           // 0..511
    int team = t >> 8;             // 0,1
    int tl = t & 255;              // thread-in-team
    int w = tl >> 6;               // wave-in-team 0..3
    int lane = t & 63;
    int ml = lane & 15, q = lane >> 4;

    int b = blk >> 4;              // batch (16 blocks per batch)
    int rbase = (blk & 15) << 3;   // first of this block's 8 receivers

    __shared__ float rtw_lds[2][2][128];   // [team][rr][sender]
    __shared__ float red[2][2][4][64];     // [team][rr][wave][o]
    __shared__ float aggL[16][68];         // rows 0..7 data, 8..15 zero, pad->68
    __shared__ unsigned short h1L[16][264];
    __shared__ unsigned short h2L[16][264];

    // zero-pad rows 8..15 (node MFMA reads 16 rows; only 8 are real)
    aggL[8 + (t >> 6)][lane] = 0.f;

    float b2c[4];
    #pragma unroll
    for (int nt = 0; nt < 4; ++nt) b2c[nt] = b2[16 * nt + ml];

    const uint4* ps4 = (const uint4*)psb + (size_t)b * (32 * NN_);   // [kc4][node]
    const uint4* w24 = (const uint4*)w2b;                            // [kc4][n]

    #pragma unroll 1
    for (int uu = 0; uu < 2; ++uu) {
        int lr = uu * 2 + team;            // local receiver-pair 0..3
        int r0 = rbase + lr * 2;           // first receiver of this unit

        __syncthreads();                   // protect rtw/red reuse across uu
        {
            int rr = tl >> 7, s = tl & 127;
            int r = r0 + rr;
            float v = 0.f;
            if (s != r) {
                int e = r * 127 + s - (s > r ? 1 : 0);
                const float* p = rt + ((size_t)(b * EDGES + e)) * 2;
                v = p[0] + p[1];
            }
            rtw_lds[team][rr][s] = v;
        }
        __syncthreads();

        int slot0 = 32 * w + ml;
        int slot1 = slot0 + 16;

        const uint4* pr4_0 = (const uint4*)(prb + ((size_t)(b * NN_ + r0)) * MH);
        const uint4* pr4_1 = (const uint4*)(prb + ((size_t)(b * NN_ + r0 + 1)) * MH);

        f32x4 acc[2][2][4];   // [receiver][m-tile][n-tile]
        #pragma unroll
        for (int rr = 0; rr < 2; ++rr)
            #pragma unroll
            for (int mt = 0; mt < 2; ++mt)
                #pragma unroll
                for (int nt = 0; nt < 4; ++nt)
                    acc[rr][mt][nt] = (f32x4){0.f, 0.f, 0.f, 0.f};

        #pragma unroll
        for (int kc = 0; kc < 8; ++kc) {
            int kc4 = 4 * kc + q;
            uint4 us0 = ps4[kc4 * NN_ + slot0];
            uint4 us1 = ps4[kc4 * NN_ + slot1];
            uint4 up0 = pr4_0[kc4];
            uint4 up1 = pr4_1[kc4];

            half8 a00 = addrelu(us0, up0);   // r0, m-tile 0
            half8 a01 = addrelu(us1, up0);   // r0, m-tile 1
            half8 a10 = addrelu(us0, up1);   // r1, m-tile 0
            half8 a11 = addrelu(us1, up1);   // r1, m-tile 1

            #pragma unroll
            for (int nt = 0; nt < 4; ++nt) {
                half8 bw = __builtin_bit_cast(half8, w24[kc4 * 64 + 16 * nt + ml]);
                acc[0][0][nt] = __builtin_amdgcn_mfma_f32_16x16x32_f16(a00, bw, acc[0][0][nt], 0, 0, 0);
                acc[0][1][nt] = __builtin_amdgcn_mfma_f32_16x16x32_f16(a01, bw, acc[0][1][nt], 0, 0, 0);
                acc[1][0][nt] = __builtin_amdgcn_mfma_f32_16x16x32_f16(a10, bw, acc[1][0][nt], 0, 0, 0);
                acc[1][1][nt] = __builtin_amdgcn_mfma_f32_16x16x32_f16(a11, bw, acc[1][1][nt], 0, 0, 0);
            }
        }

        #pragma unroll
        for (int rr = 0; rr < 2; ++rr) {
            float colsum[4] = {0.f, 0.f, 0.f, 0.f};
            #pragma unroll
            for (int mt = 0; mt < 2; ++mt) {
                int slotbase = 32 * w + 16 * mt + 4 * q;
                #pragma unroll
                for (int reg = 0; reg < 4; ++reg) {
                    float rw = rtw_lds[team][rr][slotbase + reg];
                    #pragma unroll
                    for (int nt = 0; nt < 4; ++nt)
                        colsum[nt] += fmaxf(acc[rr][mt][nt][reg] + b2c[nt], 0.f) * rw;
                }
            }
            #pragma unroll
            for (int nt = 0; nt < 4; ++nt) {
                colsum[nt] += __shfl_xor(colsum[nt], 16);
                colsum[nt] += __shfl_xor(colsum[nt], 32);
            }
            if (lane < 16) {
                #pragma unroll
                for (int nt = 0; nt < 4; ++nt)
                    red[team][rr][w][16 * nt + ml] = colsum[nt];
            }
        }
        __syncthreads();
        if (tl < 128) {
            int rr = tl >> 6, o = tl & 63;
            aggL[lr * 2 + rr][o] =
                red[team][rr][0][o] + red[team][rr][1][o] +
                red[team][rr][2][o] + red[team][rr][3][o];
        }
    }
    __syncthreads();

    // ------------------------------- node MLP -------------------------------
    int wv = t >> 6;   // wave 0..7

    half8 aA[2];
    #pragma unroll
    for (int s = 0; s < 2; ++s) {
        const float* base = &aggL[ml][32 * s + q * 8];
        aA[s] = pack8h(*(const float4*)base, *(const float4*)(base + 4));
    }

    // fc1: [16 x 64] @ [64 x 256]  (16 n-tiles over 8 waves)
    #pragma unroll
    for (int nt = 0; nt < 2; ++nt) {
        int ntg = wv * 2 + nt;
        f32x4 acc = (f32x4){0.f, 0.f, 0.f, 0.f};
        #pragma unroll
        for (int s = 0; s < 2; ++s) {
            half8 bw = *(const half8*)(o1b + (size_t)(ntg * 16 + ml) * 64 + 32 * s + q * 8);
            acc = __builtin_amdgcn_mfma_f32_16x16x32_f16(aA[s], bw, acc, 0, 0, 0);
        }
        float bv = b1o[ntg * 16 + ml];
        #pragma unroll
        for (int reg = 0; reg < 4; ++reg)
            h1L[q * 4 + reg][ntg * 16 + ml] = f2h(fmaxf(acc[reg] + bv, 0.f));
    }
    __syncthreads();

    // fc2: [16 x 256] @ [256 x 256]
    half8 aH[8];
    #pragma unroll
    for (int ks = 0; ks < 8; ++ks)
        aH[ks] = *(const half8*)&h1L[ml][32 * ks + q * 8];
    #pragma unroll
    for (int nt = 0; nt < 2; ++nt) {
        int ntg = wv * 2 + nt;
        const unsigned short* wrow = o2b + (size_t)(ntg * 16 + ml) * NH + q * 8;
        f32x4 acc = (f32x4){0.f, 0.f, 0.f, 0.f};
        #pragma unroll
        for (int ks = 0; ks < 8; ++ks) {
            half8 bw = *(const half8*)(wrow + 32 * ks);
            acc = __builtin_amdgcn_mfma_f32_16x16x32_f16(aH[ks], bw, acc, 0, 0, 0);
        }
        float bv = b2o[ntg * 16 + ml];
        #pragma unroll
        for (int reg = 0; reg < 4; ++reg)
            h2L[q * 4 + reg][ntg * 16 + ml] = f2h(fmaxf(acc[reg] + bv, 0.f));
    }
    __syncthreads();

    // fc3: [16 x 256] @ [256 x 64]  (4 n-tiles, waves 0..3)
    if (wv < 4) {
        #pragma unroll
        for (int ks = 0; ks < 8; ++ks)
            aH[ks] = *(const half8*)&h2L[ml][32 * ks + q * 8];
        const unsigned short* wrow = o3b + (size_t)(wv * 16 + ml) * NH + q * 8;
        f32x4 acc = (f32x4){0.f, 0.f, 0.f, 0.f};
        #pragma unroll
        for (int ks = 0; ks < 8; ++ks) {
            half8 bw = *(const half8*)(wrow + 32 * ks);
            acc = __builtin_amdgcn_mfma_f32_16x16x32_f16(aH[ks], bw, acc, 0, 0, 0);
        }
        float bv = b3o[wv * 16 + ml];
        if (q < 2) {   // only rows 0..7 are real
            #pragma unroll
            for (int reg = 0; reg < 4; ++reg)
                out[(size_t)(b * NN_ + rbase + q * 4 + reg) * NO + wv * 16 + ml]
                    = acc[reg] + bv;
        }
    }
}

// ---------------------------------------------------------------------------
extern "C" void kernel_launch(void* const* d_in, const int* in_sizes, int n_in,
                              void* d_out, int out_size, void* d_ws, size_t ws_size,
                              hipStream_t stream) {
    const float* x   = (const float*)d_in[0];
    const float* rt  = (const float*)d_in[3];
    const float* W1  = (const float*)d_in[4];
    const float* b1  = (const float*)d_in[5];
    const float* W2  = (const float*)d_in[6];
    const float* b2  = (const float*)d_in[7];
    const float* O1  = (const float*)d_in[8];
    const float* b1o = (const float*)d_in[9];
    const float* O2  = (const float*)d_in[10];
    const float* b2o = (const float*)d_in[11];
    const float* O3  = (const float*)d_in[12];
    const float* b3o = (const float*)d_in[13];

    float* ws  = (float*)d_ws;
    unsigned short* psb = (unsigned short*)ws;
    unsigned short* prb = (unsigned short*)(ws + 524288);
    unsigned short* w2b = (unsigned short*)(ws + 1048576);
    unsigned short* o1b = (unsigned short*)(ws + 1056768);
    unsigned short* o2b = (unsigned short*)(ws + 1064960);
    unsigned short* o3b = (unsigned short*)(ws + 1097728);
    float* out = (float*)d_out;

    hipLaunchKernelGGL(prep_kernel, dim3(704), dim3(256), 0, stream,
                       x, W1, b1, W2, O1, O2, O3, psb, prb, w2b, o1b, o2b, o3b);
    hipLaunchKernelGGL(edge_node_kernel, dim3(512), dim3(512), 0, stream,
                       rt, b2, psb, prb, w2b, o1b, b1o, o2b, b2o, o3b, b3o, out);
}

// Round 5
// 136.490 us; speedup vs baseline: 1.8761x; 1.2773x over previous
//
#include <hip/hip_runtime.h>

#define BB 32
#define NN_ 128
#define NIN 64
#define MH 256
#define MO 64
#define NH 256
#define NO 64
#define EDGES 16256

typedef _Float16 half8 __attribute__((ext_vector_type(8)));   // 8 f16 = 4 VGPRs
typedef __attribute__((ext_vector_type(4))) float f32x4;      // MFMA acc

// ws layout (floats):
//   psb: [B][32][128][8] f16   off 0        = 524288 floats
//   prb: [B][N][256]     f16   off 524288   = 524288 floats
//   w2b: [32][64][8]     f16   off 1048576  = 8192 floats
//   o1b: [256][64]       f16   off 1056768  = 8192 floats
//   o2b: [256][256]      f16   off 1064960  = 32768 floats
//   o3b: [64][256]       f16   off 1097728  = 8192 floats

static __device__ __forceinline__ unsigned short f2h(float f) {
    return __builtin_bit_cast(unsigned short, (_Float16)f);   // v_cvt_f16_f32
}

// pack 8 fp32 -> 8 f16 via 4x v_cvt_pkrtz_f16_f32 (1 inst per pair)
static __device__ __forceinline__ half8 pack8h(float4 f0, float4 f1) {
    uint4 u;
    u.x = __builtin_bit_cast(unsigned, __builtin_amdgcn_cvt_pkrtz(f0.x, f0.y));
    u.y = __builtin_bit_cast(unsigned, __builtin_amdgcn_cvt_pkrtz(f0.z, f0.w));
    u.z = __builtin_bit_cast(unsigned, __builtin_amdgcn_cvt_pkrtz(f1.x, f1.y));
    u.w = __builtin_bit_cast(unsigned, __builtin_amdgcn_cvt_pkrtz(f1.z, f1.w));
    return __builtin_bit_cast(half8, u);
}

// relu(s + p) fully in packed-f16 domain: 4x v_pk_add_f16 + 4x v_pk_max_f16
static __device__ __forceinline__ half8 addrelu(uint4 s, uint4 p) {
    half8 a = __builtin_bit_cast(half8, s) + __builtin_bit_cast(half8, p);
    half8 z = {};
    return __builtin_elementwise_max(a, z);
}

// ---------------------------------------------------------------------------
// Kernel 1: prep (unchanged).
//   blocks 0..255   : fc1 partials via f16 MFMA -> psb/prb
//   blocks 256..319 : W2 -> f16 re-layout w2b[kc4][n][k7]
//   blocks 320..703 : O1/O2/O3 -> f16 casts
// ---------------------------------------------------------------------------
__global__ __launch_bounds__(256) void prep_kernel(
    const float* __restrict__ x, const float* __restrict__ W1,
    const float* __restrict__ b1, const float* __restrict__ W2,
    const float* __restrict__ O1, const float* __restrict__ O2,
    const float* __restrict__ O3,
    unsigned short* __restrict__ psb, unsigned short* __restrict__ prb,
    unsigned short* __restrict__ w2b, unsigned short* __restrict__ o1b,
    unsigned short* __restrict__ o2b, unsigned short* __restrict__ o3b)
{
    int blk = blockIdx.x;
    int t = threadIdx.x;
    if (blk < 256) {
        int row0 = blk << 4;          // 16 consecutive global rows (b = blk>>3)
        int b = blk >> 3;
        int w = t >> 6, lane = t & 63, ml = lane & 15, q = lane >> 4;

        half8 aX[2];
        #pragma unroll
        for (int s = 0; s < 2; ++s) {
            const float* base = x + (size_t)(row0 + ml) * NIN + s * 32 + q * 8;
            aX[s] = pack8h(*(const float4*)base, *(const float4*)(base + 4));
        }

        #pragma unroll
        for (int half = 0; half < 2; ++half) {     // 0 = sender(ps), 1 = recv(pr)
            #pragma unroll
            for (int nt = 0; nt < 4; ++nt) {
                int col = w * 64 + nt * 16 + ml;   // output unit h (0..255)
                const float* wrow = W1 + (size_t)col * (2 * NIN) + half * 64 + q * 8;
                f32x4 acc = (f32x4){0.f, 0.f, 0.f, 0.f};
                #pragma unroll
                for (int s = 0; s < 2; ++s) {
                    half8 bw = pack8h(*(const float4*)(wrow + 32 * s),
                                      *(const float4*)(wrow + 32 * s + 4));
                    acc = __builtin_amdgcn_mfma_f32_16x16x32_f16(aX[s], bw, acc, 0, 0, 0);
                }
                if (half == 0) {
                    #pragma unroll
                    for (int reg = 0; reg < 4; ++reg) {
                        int n = (row0 + q * 4 + reg) & 127;
                        psb[((size_t)(b * 32 + (col >> 3)) * NN_ + n) * 8 + (col & 7)]
                            = f2h(acc[reg]);
                    }
                } else {
                    float bv = b1[col];
                    #pragma unroll
                    for (int reg = 0; reg < 4; ++reg) {
                        int n = (row0 + q * 4 + reg) & 127;
                        prb[((size_t)(b * NN_) + n) * MH + col] = f2h(acc[reg] + bv);
                    }
                }
            }
        }
    } else if (blk < 320) {
        int i = ((blk - 256) << 8) + t;   // 0..16383
        int kc4 = i >> 9, rem = i & 511;
        int n = rem >> 3, k7 = i & 7;
        w2b[i] = f2h(W2[n * MH + kc4 * 8 + k7]);   // w2b[kc4][n][k7] = W2[n][k]
    } else {
        int i = ((blk - 320) << 8) + t;   // 0..98303
        if (i < 16384)       o1b[i]         = f2h(O1[i]);
        else if (i < 81920)  o2b[i - 16384] = f2h(O2[i - 16384]);
        else                 o3b[i - 81920] = f2h(O3[i - 81920]);
    }
}

// ---------------------------------------------------------------------------
// Kernel 2: edge fc2 + segment-sum + node MLP, fused per block.
// Grid 512 x 512 threads (8 waves). Block owns 8 consecutive receivers of
// one batch, processed as 4 sequential receiver-pairs (units). ALL 8 waves
// cooperate on one unit: wave wv owns the single m-tile of senders
// [16*wv, 16*wv+16), x 4 n-tiles x 2 receivers -> acc[2][4] = 32 VGPRs.
//
// R4 post-mortem (measured): the previous team-split (acc[2][2][4]=64 regs)
// pushed the live set to ~130-160 > the 128-VGPR default cap for 512-thread
// blocks -> ~160 MB scratch spill traffic, 84 us. This layout's live set is
// ~80 regs: acc(32) + 3 in-flight uint4(12) + 2 frags(8) + bw(4) + addr.
// R3 post-mortem: __launch_bounds__(512,4) caps VGPR at 64 (cap ~= 256/arg
// empirically) -> plain (512) is correct here.
// ---------------------------------------------------------------------------
__global__ __launch_bounds__(512) void edge_node_kernel(
    const float* __restrict__ rt, const float* __restrict__ b2,
    const unsigned short* __restrict__ psb, const unsigned short* __restrict__ prb,
    const unsigned short* __restrict__ w2b,
    const unsigned short* __restrict__ o1b, const float* __restrict__ b1o,
    const unsigned short* __restrict__ o2b, const float* __restrict__ b2o,
    const unsigned short* __restrict__ o3b, const float* __restrict__ b3o,
    float* __restrict__ out)
{
    int blk = blockIdx.x;          // 0..511
    int t = threadIdx.x;           // 0..511
    int wv = t >> 6;               // wave 0..7
    int lane = t & 63;
    int ml = lane & 15, q = lane >> 4;

    int b = blk >> 4;              // batch (16 blocks per batch)
    int rbase = (blk & 15) << 3;   // first of this block's 8 receivers

    __shared__ float rtw_lds[2][128];      // [rr][sender]
    __shared__ float red[2][8][64];        // [rr][wave][o]
    __shared__ float aggL[16][68];         // rows 0..7 data, 8..15 zero, pad->68
    __shared__ unsigned short h1L[16][264];
    __shared__ unsigned short h2L[16][264];

    // zero-pad rows 8..15 (node MFMA reads 16 rows; only 8 are real)
    aggL[8 + wv][lane] = 0.f;

    float b2c[4];
    #pragma unroll
    for (int nt = 0; nt < 4; ++nt) b2c[nt] = b2[16 * nt + ml];

    const uint4* ps4 = (const uint4*)psb + (size_t)b * (32 * NN_);   // [kc4][node]
    const uint4* w24 = (const uint4*)w2b;                            // [kc4][n]

    int slot = 16 * wv + ml;       // this wave's sender m-tile

    #pragma unroll 1
    for (int un = 0; un < 4; ++un) {
        int r0 = rbase + un * 2;           // first receiver of this unit

        __syncthreads();                   // previous unit's red fully consumed
        if (t < 256) {
            int rr = t >> 7, s = t & 127;
            int r = r0 + rr;
            float v = 0.f;
            if (s != r) {
                int e = r * 127 + s - (s > r ? 1 : 0);
                const float* p = rt + ((size_t)(b * EDGES + e)) * 2;
                v = p[0] + p[1];
            }
            rtw_lds[rr][s] = v;
        }
        __syncthreads();

        const uint4* pr4_0 = (const uint4*)(prb + ((size_t)(b * NN_ + r0)) * MH);
        const uint4* pr4_1 = (const uint4*)(prb + ((size_t)(b * NN_ + r0 + 1)) * MH);

        f32x4 acc[2][4];   // [receiver][n-tile] = 32 VGPRs
        #pragma unroll
        for (int rr = 0; rr < 2; ++rr)
            #pragma unroll
            for (int nt = 0; nt < 4; ++nt)
                acc[rr][nt] = (f32x4){0.f, 0.f, 0.f, 0.f};

        #pragma unroll
        for (int kc = 0; kc < 8; ++kc) {
            int kc4 = 4 * kc + q;
            uint4 us  = ps4[kc4 * NN_ + slot];
            uint4 up0 = pr4_0[kc4];
            uint4 up1 = pr4_1[kc4];

            half8 a0 = addrelu(us, up0);   // r0
            half8 a1 = addrelu(us, up1);   // r1

            #pragma unroll
            for (int nt = 0; nt < 4; ++nt) {
                half8 bw = __builtin_bit_cast(half8, w24[kc4 * 64 + 16 * nt + ml]);
                acc[0][nt] = __builtin_amdgcn_mfma_f32_16x16x32_f16(a0, bw, acc[0][nt], 0, 0, 0);
                acc[1][nt] = __builtin_amdgcn_mfma_f32_16x16x32_f16(a1, bw, acc[1][nt], 0, 0, 0);
            }
        }

        // per-wave reduction over its 16 senders (C row = 16*wv + 4*q + reg,
        // C col = 16*nt + ml), then cross-q via shfl, then cross-wave via LDS
        #pragma unroll
        for (int rr = 0; rr < 2; ++rr) {
            float colsum[4] = {0.f, 0.f, 0.f, 0.f};
            int srow = 16 * wv + 4 * q;
            #pragma unroll
            for (int reg = 0; reg < 4; ++reg) {
                float rw = rtw_lds[rr][srow + reg];
                #pragma unroll
                for (int nt = 0; nt < 4; ++nt)
                    colsum[nt] += fmaxf(acc[rr][nt][reg] + b2c[nt], 0.f) * rw;
            }
            #pragma unroll
            for (int nt = 0; nt < 4; ++nt) {
                colsum[nt] += __shfl_xor(colsum[nt], 16);
                colsum[nt] += __shfl_xor(colsum[nt], 32);
            }
            if (lane < 16) {
                #pragma unroll
                for (int nt = 0; nt < 4; ++nt)
                    red[rr][wv][16 * nt + ml] = colsum[nt];
            }
        }
        __syncthreads();
        if (t < 128) {
            int rr = t >> 6, o = t & 63;
            float s = 0.f;
            #pragma unroll
            for (int w8 = 0; w8 < 8; ++w8) s += red[rr][w8][o];
            aggL[un * 2 + rr][o] = s;
        }
    }
    __syncthreads();

    // ------------------------------- node MLP -------------------------------
    half8 aA[2];
    #pragma unroll
    for (int s = 0; s < 2; ++s) {
        const float* base = &aggL[ml][32 * s + q * 8];
        aA[s] = pack8h(*(const float4*)base, *(const float4*)(base + 4));
    }

    // fc1: [16 x 64] @ [64 x 256]  (16 n-tiles over 8 waves)
    #pragma unroll
    for (int nt = 0; nt < 2; ++nt) {
        int ntg = wv * 2 + nt;
        f32x4 acc = (f32x4){0.f, 0.f, 0.f, 0.f};
        #pragma unroll
        for (int s = 0; s < 2; ++s) {
            half8 bw = *(const half8*)(o1b + (size_t)(ntg * 16 + ml) * 64 + 32 * s + q * 8);
            acc = __builtin_amdgcn_mfma_f32_16x16x32_f16(aA[s], bw, acc, 0, 0, 0);
        }
        float bv = b1o[ntg * 16 + ml];
        #pragma unroll
        for (int reg = 0; reg < 4; ++reg)
            h1L[q * 4 + reg][ntg * 16 + ml] = f2h(fmaxf(acc[reg] + bv, 0.f));
    }
    __syncthreads();

    // fc2: [16 x 256] @ [256 x 256]
    half8 aH[8];
    #pragma unroll
    for (int ks = 0; ks < 8; ++ks)
        aH[ks] = *(const half8*)&h1L[ml][32 * ks + q * 8];
    #pragma unroll
    for (int nt = 0; nt < 2; ++nt) {
        int ntg = wv * 2 + nt;
        const unsigned short* wrow = o2b + (size_t)(ntg * 16 + ml) * NH + q * 8;
        f32x4 acc = (f32x4){0.f, 0.f, 0.f, 0.f};
        #pragma unroll
        for (int ks = 0; ks < 8; ++ks) {
            half8 bw = *(const half8*)(wrow + 32 * ks);
            acc = __builtin_amdgcn_mfma_f32_16x16x32_f16(aH[ks], bw, acc, 0, 0, 0);
        }
        float bv = b2o[ntg * 16 + ml];
        #pragma unroll
        for (int reg = 0; reg < 4; ++reg)
            h2L[q * 4 + reg][ntg * 16 + ml] = f2h(fmaxf(acc[reg] + bv, 0.f));
    }
    __syncthreads();

    // fc3: [16 x 256] @ [256 x 64]  (4 n-tiles, waves 0..3)
    if (wv < 4) {
        #pragma unroll
        for (int ks = 0; ks < 8; ++ks)
            aH[ks] = *(const half8*)&h2L[ml][32 * ks + q * 8];
        const unsigned short* wrow = o3b + (size_t)(wv * 16 + ml) * NH + q * 8;
        f32x4 acc = (f32x4){0.f, 0.f, 0.f, 0.f};
        #pragma unroll
        for (int ks = 0; ks < 8; ++ks) {
            half8 bw = *(const half8*)(wrow + 32 * ks);
            acc = __builtin_amdgcn_mfma_f32_16x16x32_f16(aH[ks], bw, acc, 0, 0, 0);
        }
        float bv = b3o[wv * 16 + ml];
        if (q < 2) {   // only rows 0..7 are real
            #pragma unroll
            for (int reg = 0; reg < 4; ++reg)
                out[(size_t)(b * NN_ + rbase + q * 4 + reg) * NO + wv * 16 + ml]
                    = acc[reg] + bv;
        }
    }
}

// ---------------------------------------------------------------------------
extern "C" void kernel_launch(void* const* d_in, const int* in_sizes, int n_in,
                              void* d_out, int out_size, void* d_ws, size_t ws_size,
                              hipStream_t stream) {
    const float* x   = (const float*)d_in[0];
    const float* rt  = (const float*)d_in[3];
    const float* W1  = (const float*)d_in[4];
    const float* b1  = (const float*)d_in[5];
    const float* W2  = (const float*)d_in[6];
    const float* b2  = (const float*)d_in[7];
    const float* O1  = (const float*)d_in[8];
    const float* b1o = (const float*)d_in[9];
    const float* O2  = (const float*)d_in[10];
    const float* b2o = (const float*)d_in[11];
    const float* O3  = (const float*)d_in[12];
    const float* b3o = (const float*)d_in[13];

    float* ws  = (float*)d_ws;
    unsigned short* psb = (unsigned short*)ws;
    unsigned short* prb = (unsigned short*)(ws + 524288);
    unsigned short* w2b = (unsigned short*)(ws + 1048576);
    unsigned short* o1b = (unsigned short*)(ws + 1056768);
    unsigned short* o2b = (unsigned short*)(ws + 1064960);
    unsigned short* o3b = (unsigned short*)(ws + 1097728);
    float* out = (float*)d_out;

    hipLaunchKernelGGL(prep_kernel, dim3(704), dim3(256), 0, stream,
                       x, W1, b1, W2, O1, O2, O3, psb, prb, w2b, o1b, o2b, o3b);
    hipLaunchKernelGGL(edge_node_kernel, dim3(512), dim3(512), 0, stream,
                       rt, b2, psb, prb, w2b, o1b, b1o, o2b, b2o, o3b, b3o, out);
}

// Round 6
// 125.707 us; speedup vs baseline: 2.0371x; 1.0858x over previous
//
#include <hip/hip_runtime.h>

#define BB 32
#define NN_ 128
#define NIN 64
#define MH 256
#define MO 64
#define NH 256
#define NO 64
#define EDGES 16256

typedef _Float16 half8 __attribute__((ext_vector_type(8)));   // 8 f16 = 4 VGPRs
typedef __attribute__((ext_vector_type(4))) float f32x4;      // MFMA acc

// ws layout (floats):
//   psb: [B][32][128][8] f16   off 0        = 524288 floats
//   prb: [B][N][256]     f16   off 524288   = 524288 floats
//   w2b: [32][64][8]     f16   off 1048576  = 8192 floats
//   o1b: [256][64]       f16   off 1056768  = 8192 floats
//   o2b: [256][256]      f16   off 1064960  = 32768 floats
//   o3b: [64][256]       f16   off 1097728  = 8192 floats

static __device__ __forceinline__ unsigned short f2h(float f) {
    return __builtin_bit_cast(unsigned short, (_Float16)f);   // v_cvt_f16_f32
}

// pack 8 fp32 -> 8 f16 via 4x v_cvt_pkrtz_f16_f32 (1 inst per pair)
static __device__ __forceinline__ half8 pack8h(float4 f0, float4 f1) {
    uint4 u;
    u.x = __builtin_bit_cast(unsigned, __builtin_amdgcn_cvt_pkrtz(f0.x, f0.y));
    u.y = __builtin_bit_cast(unsigned, __builtin_amdgcn_cvt_pkrtz(f0.z, f0.w));
    u.z = __builtin_bit_cast(unsigned, __builtin_amdgcn_cvt_pkrtz(f1.x, f1.y));
    u.w = __builtin_bit_cast(unsigned, __builtin_amdgcn_cvt_pkrtz(f1.z, f1.w));
    return __builtin_bit_cast(half8, u);
}

// relu(s + p) fully in packed-f16 domain: 4x v_pk_add_f16 + 4x v_pk_max_f16
static __device__ __forceinline__ half8 addrelu(uint4 s, uint4 p) {
    half8 a = __builtin_bit_cast(half8, s) + __builtin_bit_cast(half8, p);
    half8 z = {};
    return __builtin_elementwise_max(a, z);
}

// ---------------------------------------------------------------------------
// Kernel 1: prep (unchanged).
//   blocks 0..255   : fc1 partials via f16 MFMA -> psb/prb
//   blocks 256..319 : W2 -> f16 re-layout w2b[kc4][n][k7]
//   blocks 320..703 : O1/O2/O3 -> f16 casts
// ---------------------------------------------------------------------------
__global__ __launch_bounds__(256) void prep_kernel(
    const float* __restrict__ x, const float* __restrict__ W1,
    const float* __restrict__ b1, const float* __restrict__ W2,
    const float* __restrict__ O1, const float* __restrict__ O2,
    const float* __restrict__ O3,
    unsigned short* __restrict__ psb, unsigned short* __restrict__ prb,
    unsigned short* __restrict__ w2b, unsigned short* __restrict__ o1b,
    unsigned short* __restrict__ o2b, unsigned short* __restrict__ o3b)
{
    int blk = blockIdx.x;
    int t = threadIdx.x;
    if (blk < 256) {
        int row0 = blk << 4;          // 16 consecutive global rows (b = blk>>3)
        int b = blk >> 3;
        int w = t >> 6, lane = t & 63, ml = lane & 15, q = lane >> 4;

        half8 aX[2];
        #pragma unroll
        for (int s = 0; s < 2; ++s) {
            const float* base = x + (size_t)(row0 + ml) * NIN + s * 32 + q * 8;
            aX[s] = pack8h(*(const float4*)base, *(const float4*)(base + 4));
        }

        #pragma unroll
        for (int half = 0; half < 2; ++half) {     // 0 = sender(ps), 1 = recv(pr)
            #pragma unroll
            for (int nt = 0; nt < 4; ++nt) {
                int col = w * 64 + nt * 16 + ml;   // output unit h (0..255)
                const float* wrow = W1 + (size_t)col * (2 * NIN) + half * 64 + q * 8;
                f32x4 acc = (f32x4){0.f, 0.f, 0.f, 0.f};
                #pragma unroll
                for (int s = 0; s < 2; ++s) {
                    half8 bw = pack8h(*(const float4*)(wrow + 32 * s),
                                      *(const float4*)(wrow + 32 * s + 4));
                    acc = __builtin_amdgcn_mfma_f32_16x16x32_f16(aX[s], bw, acc, 0, 0, 0);
                }
                if (half == 0) {
                    #pragma unroll
                    for (int reg = 0; reg < 4; ++reg) {
                        int n = (row0 + q * 4 + reg) & 127;
                        psb[((size_t)(b * 32 + (col >> 3)) * NN_ + n) * 8 + (col & 7)]
                            = f2h(acc[reg]);
                    }
                } else {
                    float bv = b1[col];
                    #pragma unroll
                    for (int reg = 0; reg < 4; ++reg) {
                        int n = (row0 + q * 4 + reg) & 127;
                        prb[((size_t)(b * NN_) + n) * MH + col] = f2h(acc[reg] + bv);
                    }
                }
            }
        }
    } else if (blk < 320) {
        int i = ((blk - 256) << 8) + t;   // 0..16383
        int kc4 = i >> 9, rem = i & 511;
        int n = rem >> 3, k7 = i & 7;
        w2b[i] = f2h(W2[n * MH + kc4 * 8 + k7]);   // w2b[kc4][n][k7] = W2[n][k]
    } else {
        int i = ((blk - 320) << 8) + t;   // 0..98303
        if (i < 16384)       o1b[i]         = f2h(O1[i]);
        else if (i < 81920)  o2b[i - 16384] = f2h(O2[i - 16384]);
        else                 o3b[i - 81920] = f2h(O3[i - 81920]);
    }
}

// ---------------------------------------------------------------------------
// Kernel 2: edge fc2 + segment-sum + node MLP, fused per block.
// Grid 512 x 512 threads (8 waves). Block owns 8 consecutive receivers of
// one batch, processed as 4 sequential receiver-pairs (units). Wave wv owns
// senders [16*wv, 16*wv+16) x 4 n-tiles x 2 receivers -> acc[2][4] = 32 regs.
//
// R5 post-mortem (measured): 48 us at HBM 3.5% / Mfma 13.5 / Occ 18 -- L2-
// redundancy bound: each wave refetched all of w2b per unit (1 MB/block) and
// its ps slice per unit (4x) => ~900 MB L2 reads ~= 19 TB/s. All of that is
// unit-invariant. Fix: w2b staged to LDS once (32 KB), us hoisted to regs
// (usr[8], 32 VGPRs, reused across units), rtw for all 4 units preloaded.
// Live set ~110 regs < the 128 default cap for 512-thr blocks (R4 law;
// R3 law: never use __launch_bounds__ 2nd arg here -- it caps VGPR=256/arg).
// ---------------------------------------------------------------------------
__global__ __launch_bounds__(512) void edge_node_kernel(
    const float* __restrict__ rt, const float* __restrict__ b2,
    const unsigned short* __restrict__ psb, const unsigned short* __restrict__ prb,
    const unsigned short* __restrict__ w2b,
    const unsigned short* __restrict__ o1b, const float* __restrict__ b1o,
    const unsigned short* __restrict__ o2b, const float* __restrict__ b2o,
    const unsigned short* __restrict__ o3b, const float* __restrict__ b3o,
    float* __restrict__ out)
{
    int blk = blockIdx.x;          // 0..511
    int t = threadIdx.x;           // 0..511
    int wv = t >> 6;               // wave 0..7
    int lane = t & 63;
    int ml = lane & 15, q = lane >> 4;

    int b = blk >> 4;              // batch (16 blocks per batch)
    int rbase = (blk & 15) << 3;   // first of this block's 8 receivers

    __shared__ uint4 w2L[2048];            // 32 KB: full W2 tile, staged once
    __shared__ float rtwA[4][2][128];      // 4 KB: all 4 units' rt weights
    __shared__ float red[2][8][64];        // [rr][wave][o]
    __shared__ float aggL[16][68];         // rows 0..7 data, 8..15 zero, pad->68
    __shared__ unsigned short h1L[16][264];
    __shared__ unsigned short h2L[16][264];

    // ---- one-time staging (all unit-invariant data) ----
    {
        const uint4* w24 = (const uint4*)w2b;
        #pragma unroll
        for (int i = 0; i < 4; ++i)        // lane-consecutive: conflict-free
            w2L[t + 512 * i] = w24[t + 512 * i];
    }
    #pragma unroll
    for (int j = 0; j < 2; ++j) {          // rtw for all 4 units
        int idx = 2 * t + j;               // 0..1023
        int un = idx >> 8, rr = (idx >> 7) & 1, s = idx & 127;
        int r = rbase + un * 2 + rr;
        float v = 0.f;
        if (s != r) {
            int e = r * 127 + s - (s > r ? 1 : 0);
            const float* p = rt + ((size_t)(b * EDGES + e)) * 2;
            v = p[0] + p[1];
        }
        rtwA[un][rr][s] = v;
    }

    // zero-pad rows 8..15 (node MFMA reads 16 rows; only 8 are real)
    aggL[8 + wv][lane] = 0.f;

    float b2c[4];
    #pragma unroll
    for (int nt = 0; nt < 4; ++nt) b2c[nt] = b2[16 * nt + ml];

    // sender fragments: loaded ONCE, live across all 4 units (32 VGPRs)
    int slot = 16 * wv + ml;
    uint4 usr[8];
    {
        const uint4* ps4 = (const uint4*)psb + (size_t)b * (32 * NN_);
        #pragma unroll
        for (int kc = 0; kc < 8; ++kc)
            usr[kc] = ps4[(4 * kc + q) * NN_ + slot];
    }

    __syncthreads();   // w2L + rtwA ready

    #pragma unroll 1
    for (int un = 0; un < 4; ++un) {
        int r0 = rbase + un * 2;           // first receiver of this unit
        const uint4* pr4_0 = (const uint4*)(prb + ((size_t)(b * NN_ + r0)) * MH);
        const uint4* pr4_1 = (const uint4*)(prb + ((size_t)(b * NN_ + r0 + 1)) * MH);

        f32x4 acc[2][4];   // [receiver][n-tile] = 32 VGPRs
        #pragma unroll
        for (int rr = 0; rr < 2; ++rr)
            #pragma unroll
            for (int nt = 0; nt < 4; ++nt)
                acc[rr][nt] = (f32x4){0.f, 0.f, 0.f, 0.f};

        #pragma unroll
        for (int kc = 0; kc < 8; ++kc) {
            int kc4 = 4 * kc + q;
            uint4 up0 = pr4_0[kc4];        // broadcast within 16-lane group
            uint4 up1 = pr4_1[kc4];

            half8 a0 = addrelu(usr[kc], up0);   // r0
            half8 a1 = addrelu(usr[kc], up1);   // r1

            #pragma unroll
            for (int nt = 0; nt < 4; ++nt) {
                half8 bw = __builtin_bit_cast(half8, w2L[kc4 * 64 + 16 * nt + ml]);
                acc[0][nt] = __builtin_amdgcn_mfma_f32_16x16x32_f16(a0, bw, acc[0][nt], 0, 0, 0);
                acc[1][nt] = __builtin_amdgcn_mfma_f32_16x16x32_f16(a1, bw, acc[1][nt], 0, 0, 0);
            }
        }

        // per-wave reduction over its 16 senders (C row = 16*wv + 4*q + reg,
        // C col = 16*nt + ml), then cross-q via shfl, then cross-wave via LDS
        #pragma unroll
        for (int rr = 0; rr < 2; ++rr) {
            float colsum[4] = {0.f, 0.f, 0.f, 0.f};
            int srow = 16 * wv + 4 * q;
            #pragma unroll
            for (int reg = 0; reg < 4; ++reg) {
                float rw = rtwA[un][rr][srow + reg];
                #pragma unroll
                for (int nt = 0; nt < 4; ++nt)
                    colsum[nt] += fmaxf(acc[rr][nt][reg] + b2c[nt], 0.f) * rw;
            }
            #pragma unroll
            for (int nt = 0; nt < 4; ++nt) {
                colsum[nt] += __shfl_xor(colsum[nt], 16);
                colsum[nt] += __shfl_xor(colsum[nt], 32);
            }
            if (lane < 16) {
                #pragma unroll
                for (int nt = 0; nt < 4; ++nt)
                    red[rr][wv][16 * nt + ml] = colsum[nt];
            }
        }
        __syncthreads();                   // red complete
        if (t < 128) {
            int rr = t >> 6, o = t & 63;
            float s = 0.f;
            #pragma unroll
            for (int w8 = 0; w8 < 8; ++w8) s += red[rr][w8][o];
            aggL[un * 2 + rr][o] = s;
        }
        __syncthreads();                   // red consumed; next unit may write
    }

    // ------------------------------- node MLP -------------------------------
    half8 aA[2];
    #pragma unroll
    for (int s = 0; s < 2; ++s) {
        const float* base = &aggL[ml][32 * s + q * 8];
        aA[s] = pack8h(*(const float4*)base, *(const float4*)(base + 4));
    }

    // fc1: [16 x 64] @ [64 x 256]  (16 n-tiles over 8 waves)
    #pragma unroll
    for (int nt = 0; nt < 2; ++nt) {
        int ntg = wv * 2 + nt;
        f32x4 acc = (f32x4){0.f, 0.f, 0.f, 0.f};
        #pragma unroll
        for (int s = 0; s < 2; ++s) {
            half8 bw = *(const half8*)(o1b + (size_t)(ntg * 16 + ml) * 64 + 32 * s + q * 8);
            acc = __builtin_amdgcn_mfma_f32_16x16x32_f16(aA[s], bw, acc, 0, 0, 0);
        }
        float bv = b1o[ntg * 16 + ml];
        #pragma unroll
        for (int reg = 0; reg < 4; ++reg)
            h1L[q * 4 + reg][ntg * 16 + ml] = f2h(fmaxf(acc[reg] + bv, 0.f));
    }
    __syncthreads();

    // fc2: [16 x 256] @ [256 x 256]
    half8 aH[8];
    #pragma unroll
    for (int ks = 0; ks < 8; ++ks)
        aH[ks] = *(const half8*)&h1L[ml][32 * ks + q * 8];
    #pragma unroll
    for (int nt = 0; nt < 2; ++nt) {
        int ntg = wv * 2 + nt;
        const unsigned short* wrow = o2b + (size_t)(ntg * 16 + ml) * NH + q * 8;
        f32x4 acc = (f32x4){0.f, 0.f, 0.f, 0.f};
        #pragma unroll
        for (int ks = 0; ks < 8; ++ks) {
            half8 bw = *(const half8*)(wrow + 32 * ks);
            acc = __builtin_amdgcn_mfma_f32_16x16x32_f16(aH[ks], bw, acc, 0, 0, 0);
        }
        float bv = b2o[ntg * 16 + ml];
        #pragma unroll
        for (int reg = 0; reg < 4; ++reg)
            h2L[q * 4 + reg][ntg * 16 + ml] = f2h(fmaxf(acc[reg] + bv, 0.f));
    }
    __syncthreads();

    // fc3: [16 x 256] @ [256 x 64]  (4 n-tiles, waves 0..3)
    if (wv < 4) {
        #pragma unroll
        for (int ks = 0; ks < 8; ++ks)
            aH[ks] = *(const half8*)&h2L[ml][32 * ks + q * 8];
        const unsigned short* wrow = o3b + (size_t)(wv * 16 + ml) * NH + q * 8;
        f32x4 acc = (f32x4){0.f, 0.f, 0.f, 0.f};
        #pragma unroll
        for (int ks = 0; ks < 8; ++ks) {
            half8 bw = *(const half8*)(wrow + 32 * ks);
            acc = __builtin_amdgcn_mfma_f32_16x16x32_f16(aH[ks], bw, acc, 0, 0, 0);
        }
        float bv = b3o[wv * 16 + ml];
        if (q < 2) {   // only rows 0..7 are real
            #pragma unroll
            for (int reg = 0; reg < 4; ++reg)
                out[(size_t)(b * NN_ + rbase + q * 4 + reg) * NO + wv * 16 + ml]
                    = acc[reg] + bv;
        }
    }
}

// ---------------------------------------------------------------------------
extern "C" void kernel_launch(void* const* d_in, const int* in_sizes, int n_in,
                              void* d_out, int out_size, void* d_ws, size_t ws_size,
                              hipStream_t stream) {
    const float* x   = (const float*)d_in[0];
    const float* rt  = (const float*)d_in[3];
    const float* W1  = (const float*)d_in[4];
    const float* b1  = (const float*)d_in[5];
    const float* W2  = (const float*)d_in[6];
    const float* b2  = (const float*)d_in[7];
    const float* O1  = (const float*)d_in[8];
    const float* b1o = (const float*)d_in[9];
    const float* O2  = (const float*)d_in[10];
    const float* b2o = (const float*)d_in[11];
    const float* O3  = (const float*)d_in[12];
    const float* b3o = (const float*)d_in[13];

    float* ws  = (float*)d_ws;
    unsigned short* psb = (unsigned short*)ws;
    unsigned short* prb = (unsigned short*)(ws + 524288);
    unsigned short* w2b = (unsigned short*)(ws + 1048576);
    unsigned short* o1b = (unsigned short*)(ws + 1056768);
    unsigned short* o2b = (unsigned short*)(ws + 1064960);
    unsigned short* o3b = (unsigned short*)(ws + 1097728);
    float* out = (float*)d_out;

    hipLaunchKernelGGL(prep_kernel, dim3(704), dim3(256), 0, stream,
                       x, W1, b1, W2, O1, O2, O3, psb, prb, w2b, o1b, o2b, o3b);
    hipLaunchKernelGGL(edge_node_kernel, dim3(512), dim3(512), 0, stream,
                       rt, b2, psb, prb, w2b, o1b, b1o, o2b, b2o, o3b, b3o, out);
}